// Round 8
// baseline (502.332 us; speedup 1.0000x reference)
//
#include <hip/hip_runtime.h>
#include <hip/hip_fp16.h>
#include <math.h>

#define HID 32
#define NFEAT 100
#define CHUNK 4096   // edges per chunk in kc_sort
#define NCMAX 512    // max chunks (E/CHUNK = 391)
#define NBMAX 1024   // max buckets (N/128 = 782)
#define LOCB 128     // nodes per bucket
#define ASTR 33      // acc row stride: 32 acc + 1 dsum (33 odd -> bank-spread)

typedef _Float16 half2_v __attribute__((ext_vector_type(2)));
__device__ __forceinline__ float dot2h(unsigned int a, unsigned int b, float c) {
    return __builtin_amdgcn_fdot2(*(half2_v*)&a, *(half2_v*)&b, c, false);
}

// ---------------- K1 (R6 form): xh = fp16(relu(X@w1^T+b1)); invn = 1/max(||x||,1e-12) -----
__global__ __launch_bounds__(256) void k1_lin1_norm(
    const float* __restrict__ X, const float* __restrict__ w1,
    const float* __restrict__ b1,
    __half* __restrict__ xh, float* __restrict__ invn, int N)
{
    __shared__ float wT[NFEAT * 33];   // wT[k*33+h], conflict-free by h
    __shared__ float4 xs4[64 * 25];    // xs4[node*25 + kq]
    const int tid = threadIdx.x;
    const float4* w14 = (const float4*)w1;   // 32*100 floats = 800 float4
    for (int i = tid; i < 800; i += 256) {
        float4 v = w14[i];
        int idx = i * 4, h = idx / NFEAT, k = idx % NFEAT;
        wT[k * 33 + h] = v.x; wT[(k + 1) * 33 + h] = v.y;
        wT[(k + 2) * 33 + h] = v.z; wT[(k + 3) * 33 + h] = v.w;
    }
    const int n0 = blockIdx.x * 64;
    const float4* X4 = (const float4*)X;     // row = 25 float4
    for (int i = tid; i < 1600; i += 256) {
        int r = i / 25, q = i % 25;
        int node = n0 + r;
        xs4[i] = (node < N) ? X4[(size_t)node * 25 + q] : make_float4(0.f, 0.f, 0.f, 0.f);
    }
    __syncthreads();

    const int h  = tid & 31;
    const int ng = tid >> 5;    // node group 0..7 (8 nodes each)
    const float bb = b1[h];
    float d[8] = {0.f, 0.f, 0.f, 0.f, 0.f, 0.f, 0.f, 0.f};

    #pragma unroll 5
    for (int kq = 0; kq < 25; ++kq) {
        const int kb = kq * 4;
        const float wa = wT[kb * 33 + h];
        const float wb = wT[(kb + 1) * 33 + h];
        const float wc = wT[(kb + 2) * 33 + h];
        const float wd = wT[(kb + 3) * 33 + h];
        #pragma unroll
        for (int j = 0; j < 8; ++j) {
            float4 xv = xs4[(ng * 8 + j) * 25 + kq];
            d[j] = fmaf(xv.x, wa, d[j]);
            d[j] = fmaf(xv.y, wb, d[j]);
            d[j] = fmaf(xv.z, wc, d[j]);
            d[j] = fmaf(xv.w, wd, d[j]);
        }
    }
    #pragma unroll
    for (int j = 0; j < 8; ++j) {
        float v = fmaxf(d[j] + bb, 0.f);
        float s = v * v;
        #pragma unroll
        for (int m = 16; m >= 1; m >>= 1) s += __shfl_xor(s, m, 32);
        float inv = 1.f / fmaxf(sqrtf(s), 1e-12f);
        int node = n0 + ng * 8 + j;
        if (node < N) {
            xh[(size_t)node * HID + h] = __float2half(v);
            if (h == 0) invn[node] = inv;
        }
    }
}

// ---------------- Chunk-local bucket sort (bucket = tgt>>7); coalesced u16 offsets ----------
__global__ __launch_bounds__(256) void kc_sort(
    const int* __restrict__ ei, int* __restrict__ binned,
    unsigned short* __restrict__ offU, int E, int NB, int NC)
{
    __shared__ int hist[NBMAX];
    __shared__ int off[NBMAX];
    const int tid = threadIdx.x;
    const int c = blockIdx.x;
    const int start = c * CHUNK;
    const int end = min(start + CHUNK, E);
    for (int b = tid; b < NB; b += 256) hist[b] = 0;
    __syncthreads();
    for (int e = start + tid; e < end; e += 256)
        atomicAdd(&hist[ei[E + e] >> 7], 1);
    __syncthreads();
    if (tid < 64) {   // wave 0: exclusive scan, 64 buckets/round with carry
        int carry = 0;
        for (int r = 0; r * 64 < NB; ++r) {
            int b = r * 64 + tid;
            int v = (b < NB) ? hist[b] : 0;
            int x = v;
            #pragma unroll
            for (int dd = 1; dd < 64; dd <<= 1) {
                int y = __shfl_up(x, dd, 64);
                if (tid >= dd) x += y;
            }
            if (b < NB) off[b] = carry + x - v;
            carry += __shfl(x, 63, 64);
        }
    }
    __syncthreads();
    const size_t urow = (size_t)c * (NB + 1);
    for (int b = tid; b < NB; b += 256) {
        offU[urow + b] = (unsigned short)off[b];
        hist[b] = off[b];               // reuse as local cursor
    }
    if (tid == 0) offU[urow + NB] = (unsigned short)(end - start);
    __syncthreads();
    for (int e = start + tid; e < end; e += 256) {
        int t = ei[E + e];
        int b = t >> 7;
        int pos = atomicAdd(&hist[b], 1);
        binned[start + pos] = ei[e] | ((t & 127) << 17);  // src<2^17, local 7 bits
    }
}

// ---------------- Transpose offU [C][R] u16 -> offT [R][C] (R=NB+1, C=NC) ----------------
__global__ __launch_bounds__(256) void k_transpose(
    const unsigned short* __restrict__ in, unsigned short* __restrict__ outp, int R, int C)
{
    __shared__ unsigned short tile[64][65];
    const int b0 = blockIdx.x * 64, c0 = blockIdx.y * 64;
    const int tx = threadIdx.x & 63, ty0 = threadIdx.x >> 6;
    for (int ty = ty0; ty < 64; ty += 4) {
        int c = c0 + ty, b = b0 + tx;
        tile[ty][tx] = (c < C && b < R) ? in[(size_t)c * R + b] : 0;
    }
    __syncthreads();
    for (int ty = ty0; ty < 64; ty += 4) {
        int b = b0 + ty, c = c0 + tx;
        if (b < R && c < C) outp[(size_t)b * C + c] = tile[tx][ty];
    }
}

// ---------------- Fused streaming: edges -> LDS fp32 accumulators (ds_add), no grouping ----
// Block = bucket of 128 target nodes. Balanced per-thread edge ranges via LDS prefix.
__global__ __launch_bounds__(256) void k_fused(
    const int* __restrict__ binned, const unsigned short* __restrict__ offT,
    const __half* __restrict__ xh, const float* __restrict__ invn,
    const float* __restrict__ pbeta,
    const float* __restrict__ w2, const float* __restrict__ b2,
    float* __restrict__ out, int N, int NB, int NC)
{
    __shared__ float accf[LOCB * ASTR];                       // 16.9 KB
    __shared__ unsigned short b0s[NCMAX], b1s[NCMAX];         // 2 KB
    __shared__ unsigned short pfx[NCMAX + 1];                 // 1 KB
    const int tid = threadIdx.x;
    const int b = blockIdx.x;
    const int nodeBase = b * LOCB;
    const float beta = *pbeta;

    for (int i = tid; i < LOCB * ASTR; i += 256) accf[i] = 0.f;
    for (int c = tid; c < NC; c += 256) {
        b0s[c] = offT[(size_t)b * NC + c];
        b1s[c] = offT[(size_t)(b + 1) * NC + c];
    }
    __syncthreads();
    if (tid < 64) {   // wave 0: exclusive scan of run lengths -> pfx
        int carry = 0;
        for (int r = 0; r * 64 < NC; ++r) {
            int c = r * 64 + tid;
            int v = (c < NC) ? (int)b1s[c] - (int)b0s[c] : 0;
            int x = v;
            #pragma unroll
            for (int dd = 1; dd < 64; dd <<= 1) {
                int y = __shfl_up(x, dd, 64);
                if (tid >= dd) x += y;
            }
            if (c < NC) pfx[c] = (unsigned short)(carry + x - v);
            carry += __shfl(x, 63, 64);
        }
        if (tid == 0) pfx[NC] = (unsigned short)carry;
    }
    __syncthreads();
    const int sz = pfx[NC];

    // balanced range [e0,e1) for this thread
    const int e0 = (int)(((long long)tid * sz) >> 8);
    const int e1 = (int)(((long long)(tid + 1) * sz) >> 8);
    int cnt = e1 - e0;
    if (cnt > 0) {
        int lo = 0, hi = NC;           // find c: pfx[c] <= e0 < pfx[c+1]
        while (hi - lo > 1) {
            int mid = (lo + hi) >> 1;
            if ((int)pfx[mid] <= e0) lo = mid; else hi = mid;
        }
        int c = lo;
        int j = (int)b0s[c] + (e0 - (int)pfx[c]);
        int j1 = (int)b1s[c];
        while (cnt > 0) {
            while (j >= j1) { ++c; j = b0s[c]; j1 = b1s[c]; }
            const int w = binned[c * CHUNK + j]; ++j; --cnt;
            const int local = w >> 17;
            const int src = w & 0x1FFFF;
            const __half* sr = xh + (size_t)src * HID;
            const __half* tr = xh + (size_t)(nodeBase + local) * HID;  // L1-hot (8 KB/block)
            union { uint4 u[4]; __half2 h[16]; unsigned int w[16]; } S, T;
            S.u[0] = ((const uint4*)sr)[0]; S.u[1] = ((const uint4*)sr)[1];
            S.u[2] = ((const uint4*)sr)[2]; S.u[3] = ((const uint4*)sr)[3];
            T.u[0] = ((const uint4*)tr)[0]; T.u[1] = ((const uint4*)tr)[1];
            T.u[2] = ((const uint4*)tr)[2]; T.u[3] = ((const uint4*)tr)[3];
            float p = 0.f;
            #pragma unroll
            for (int k = 0; k < 16; ++k) p = dot2h(T.w[k], S.w[k], p);
            const float wgt = __expf(beta * p * invn[src] * invn[nodeBase + local]);
            float* ar = accf + local * ASTR;
            #pragma unroll
            for (int k = 0; k < 16; ++k) {
                float2 f = __half22float2(S.h[k]);
                atomicAdd(ar + 2 * k,     wgt * f.x);
                atomicAdd(ar + 2 * k + 1, wgt * f.y);
            }
            atomicAdd(ar + 32, wgt);
        }
    }
    __syncthreads();

    // epilogue: one thread per node
    if (tid < LOCB) {
        const int node = nodeBase + tid;
        if (node < N) {
            const float ivt = invn[node];
            union { uint4 u[4]; __half2 h[16]; unsigned int w[16]; } T;
            const uint4* xr = (const uint4*)(xh + (size_t)node * HID);
            T.u[0] = xr[0]; T.u[1] = xr[1]; T.u[2] = xr[2]; T.u[3] = xr[3];
            float sd = 0.f;
            #pragma unroll
            for (int k = 0; k < 16; ++k) sd = dot2h(T.w[k], T.w[k], sd);
            const float wself = __expf(beta * sd * ivt * ivt);
            float* ar = accf + tid * ASTR;
            const float invd = 1.f / (ar[32] + wself);
            float l0 = 0.f, l1 = 0.f;
            #pragma unroll
            for (int k = 0; k < 16; ++k) {
                float2 f = __half22float2(T.h[k]);
                float o0 = (ar[2 * k]     + wself * f.x) * invd;
                float o1 = (ar[2 * k + 1] + wself * f.y) * invd;
                l0 += o0 * w2[2 * k] + o1 * w2[2 * k + 1];
                l1 += o0 * w2[HID + 2 * k] + o1 * w2[HID + 2 * k + 1];
            }
            l0 += b2[0]; l1 += b2[1];
            float m = fmaxf(l0, l1);
            float lse = m + __logf(__expf(l0 - m) + __expf(l1 - m));
            out[2 * (size_t)node]     = l0 - lse;
            out[2 * (size_t)node + 1] = l1 - lse;
        }
    }
}

extern "C" void kernel_launch(void* const* d_in, const int* in_sizes, int n_in,
                              void* d_out, int out_size, void* d_ws, size_t ws_size,
                              hipStream_t stream) {
    const float* X    = (const float*)d_in[0];
    const float* w1   = (const float*)d_in[1];
    const float* b1   = (const float*)d_in[2];
    const float* beta = (const float*)d_in[3];
    const float* w2   = (const float*)d_in[4];
    const float* b2   = (const float*)d_in[5];
    const int*   ei   = (const int*)d_in[6];

    const int N = in_sizes[0] / NFEAT;        // 100000
    const int E = in_sizes[6] / 2;            // 1600000
    const int NB = (N + LOCB - 1) / LOCB;     // 782 buckets of 128 nodes
    const int NC = (E + CHUNK - 1) / CHUNK;   // 391 chunks
    const int R  = NB + 1;                    // offset-table rows

    char* wsb = (char*)d_ws;
    __half* xhp  = (__half*)wsb;          wsb += (size_t)N * HID * 2;   // 6.4 MB
    float* invn  = (float*)wsb;           wsb += (size_t)N * 4;
    int*   binned = (int*)wsb;            wsb += (size_t)E * 4;         // 6.4 MB
    unsigned short* offU = (unsigned short*)wsb; wsb += (size_t)R * NC * 2;
    unsigned short* offT = (unsigned short*)wsb; wsb += (size_t)R * NC * 2;
    float* out   = (float*)d_out;

    k1_lin1_norm<<<(N + 63) / 64, 256, 0, stream>>>(X, w1, b1, xhp, invn, N);
    kc_sort<<<NC, 256, 0, stream>>>(ei, binned, offU, E, NB, NC);
    k_transpose<<<dim3((R + 63) / 64, (NC + 63) / 64), 256, 0, stream>>>(offU, offT, R, NC);
    k_fused<<<NB, 256, 0, stream>>>(binned, offT, xhp, invn, beta, w2, b2, out, N, NB, NC);
}

// Round 9
// 228.845 us; speedup vs baseline: 2.1951x; 2.1951x over previous
//
#include <hip/hip_runtime.h>
#include <hip/hip_fp16.h>
#include <math.h>

#define HID 32
#define NFEAT 100
#define CHUNK 4096   // edges per sort chunk
#define NCMAX 512    // max chunks (E/CHUNK = 391)
#define NBMAX 1024   // max buckets (N/128 = 782)
#define LOCB 128     // target nodes per bucket (7-bit local id)
#define CAP 2560     // LDS edge capacity per bucket (mean 2048, sd 45 -> +11 sigma)

typedef _Float16 half2_v __attribute__((ext_vector_type(2)));
__device__ __forceinline__ float2 h2f(unsigned int u) {
    return __half22float2(*(__half2*)&u);
}
__device__ __forceinline__ float4 h4_to_f4(uint2 u) {
    float2 a = h2f(u.x), b = h2f(u.y);
    return make_float4(a.x, a.y, b.x, b.y);
}

// ================= Phase 1 (single dispatch): k1 blocks + sort-chunk blocks =================
// blocks [0, nblk1): lin1+relu+norm -> xh (fp16), invn.   64 nodes/block.
// blocks [nblk1, nblk1+NC): chunk-local bucket sort of edges by tgt>>7 -> binned, offU.
__global__ __launch_bounds__(256) void k_phase1(
    const float* __restrict__ X, const float* __restrict__ w1,
    const float* __restrict__ b1, const int* __restrict__ ei,
    __half* __restrict__ xh, float* __restrict__ invn,
    int* __restrict__ binned, unsigned short* __restrict__ offU,
    int N, int E, int NB, int NC, int nblk1)
{
    __shared__ __align__(16) char smem[26048];
    const int tid = threadIdx.x;

    if (blockIdx.x < nblk1) {
        // ---------------- k1: xh = fp16(relu(X@w1^T+b1)); invn = 1/max(||x||,eps) ----------
        float*   wT  = (float*)smem;                    // [100][33] fp32, 13200 B
        __half2* xsH = (__half2*)(smem + 13216);        // [64][50] half2, 12800 B
        const float4* w14 = (const float4*)w1;          // 800 float4
        for (int i = tid; i < 800; i += 256) {
            float4 v = w14[i];
            int idx = i * 4, h = idx / NFEAT, k = idx % NFEAT;
            wT[k * 33 + h] = v.x; wT[(k + 1) * 33 + h] = v.y;
            wT[(k + 2) * 33 + h] = v.z; wT[(k + 3) * 33 + h] = v.w;
        }
        const int n0 = blockIdx.x * 64;
        const float4* X4 = (const float4*)X;            // row = 25 float4
        for (int i = tid; i < 1600; i += 256) {
            int r = i / 25, q = i % 25;
            int node = n0 + r;
            float4 v = (node < N) ? X4[(size_t)node * 25 + q] : make_float4(0.f, 0.f, 0.f, 0.f);
            xsH[r * 50 + 2 * q]     = __floats2half2_rn(v.x, v.y);
            xsH[r * 50 + 2 * q + 1] = __floats2half2_rn(v.z, v.w);
        }
        __syncthreads();

        const int h  = tid & 31;
        const int ng = tid >> 5;    // node group 0..7 (8 nodes each)
        const float bb = b1[h];
        float d[8] = {0.f, 0.f, 0.f, 0.f, 0.f, 0.f, 0.f, 0.f};

        #pragma unroll 5
        for (int kq = 0; kq < 25; ++kq) {
            const int kb = kq * 4;
            const float wa = wT[kb * 33 + h];
            const float wb = wT[(kb + 1) * 33 + h];
            const float wc = wT[(kb + 2) * 33 + h];
            const float wd = wT[(kb + 3) * 33 + h];
            #pragma unroll
            for (int j = 0; j < 8; ++j) {
                uint2 u = *(const uint2*)&xsH[(ng * 8 + j) * 50 + 2 * kq];
                float2 fa = h2f(u.x), fb = h2f(u.y);
                d[j] = fmaf(fa.x, wa, d[j]);
                d[j] = fmaf(fa.y, wb, d[j]);
                d[j] = fmaf(fb.x, wc, d[j]);
                d[j] = fmaf(fb.y, wd, d[j]);
            }
        }
        #pragma unroll
        for (int j = 0; j < 8; ++j) {
            float v = fmaxf(d[j] + bb, 0.f);
            float s = v * v;
            #pragma unroll
            for (int m = 16; m >= 1; m >>= 1) s += __shfl_xor(s, m, 32);
            float inv = 1.f / fmaxf(sqrtf(s), 1e-12f);
            int node = n0 + ng * 8 + j;
            if (node < N) {
                xh[(size_t)node * HID + h] = __float2half(v);
                if (h == 0) invn[node] = inv;
            }
        }
    } else {
        // ---------------- kc_sort: chunk-local counting sort by bucket = tgt>>7 ------------
        int* hist = (int*)smem;          // NBMAX ints
        int* off  = hist + NBMAX;        // NBMAX ints
        const int c = blockIdx.x - nblk1;
        const int start = c * CHUNK;
        const int end = min(start + CHUNK, E);
        for (int b = tid; b < NB; b += 256) hist[b] = 0;
        __syncthreads();
        for (int e = start + tid; e < end; e += 256)
            atomicAdd(&hist[ei[E + e] >> 7], 1);
        __syncthreads();
        if (tid < 64) {   // wave 0: exclusive scan, 64 buckets/round with carry
            int carry = 0;
            for (int r = 0; r * 64 < NB; ++r) {
                int b = r * 64 + tid;
                int v = (b < NB) ? hist[b] : 0;
                int x = v;
                #pragma unroll
                for (int dd = 1; dd < 64; dd <<= 1) {
                    int y = __shfl_up(x, dd, 64);
                    if (tid >= dd) x += y;
                }
                if (b < NB) off[b] = carry + x - v;
                carry += __shfl(x, 63, 64);
            }
        }
        __syncthreads();
        const size_t urow = (size_t)c * (NB + 1);
        for (int b = tid; b < NB; b += 256) {
            offU[urow + b] = (unsigned short)off[b];   // coalesced u16 writes
            hist[b] = off[b];                           // reuse as local cursor
        }
        if (tid == 0) offU[urow + NB] = (unsigned short)(end - start);
        __syncthreads();
        for (int e = start + tid; e < end; e += 256) {
            int t = ei[E + e];
            int b = t >> 7;
            int pos = atomicAdd(&hist[b], 1);
            binned[start + pos] = ei[e] | ((t & 127) << 17);  // src<2^17, local 7 bits
        }
    }
}

// ================= Fused: 2-pass LDS group (R6 structure) + gather + lin2 + lsm =============
// Block = bucket of 128 targets. Reads offU untransposed (b0/b1 adjacent u16, L2-resident).
__global__ __launch_bounds__(256) void k_fused(
    const int* __restrict__ binned, const unsigned short* __restrict__ offU,
    const __half* __restrict__ xh, const float* __restrict__ invn,
    const float* __restrict__ pbeta,
    const float* __restrict__ w2, const float* __restrict__ b2,
    float* __restrict__ out, int N, int NB, int NC)
{
    __shared__ unsigned short b0s[NCMAX], b1s[NCMAX];
    __shared__ int cnt[LOCB], cur[LOCB];
    __shared__ int led[CAP];
    __shared__ int ovf;
    const int tid  = threadIdx.x;
    const int lane = tid & 63;
    const int wv   = tid >> 6;
    const int g    = lane & 7;   // feature slice: halfs g*4 .. g*4+3
    const int sub  = lane >> 3;  // edge slot 0..7
    const int b    = blockIdx.x;
    const int R    = NB + 1;
    const float beta = *pbeta;
    const float w0a = w2[g*4], w0b = w2[g*4+1], w0c = w2[g*4+2], w0d = w2[g*4+3];
    const float w1a = w2[HID+g*4], w1b = w2[HID+g*4+1], w1c = w2[HID+g*4+2], w1d = w2[HID+g*4+3];
    const float bb0 = b2[0], bb1 = b2[1];

    for (int c = tid; c < NC; c += 256) {
        const size_t base = (size_t)c * R + b;
        b0s[c] = offU[base];
        b1s[c] = offU[base + 1];
    }
    for (int i = tid; i < LOCB; i += 256) cnt[i] = 0;
    if (tid == 0) ovf = 0;
    __syncthreads();
    // pass A: per-node degree counts
    for (int c = tid; c < NC; c += 256) {
        const int gbase = c * CHUNK;
        const int j1 = b1s[c];
        for (int j = b0s[c]; j < j1; ++j)
            atomicAdd(&cnt[binned[gbase + j] >> 17], 1);
    }
    __syncthreads();
    if (tid < 64) {   // exclusive scan of 128 counts (2 rounds of 64 with carry)
        int carry = 0;
        #pragma unroll
        for (int r = 0; r < 2; ++r) {
            int idx = r * 64 + tid;
            int v = cnt[idx], x = v;
            #pragma unroll
            for (int dd = 1; dd < 64; dd <<= 1) {
                int y = __shfl_up(x, dd, 64);
                if (tid >= dd) x += y;
            }
            cur[idx] = carry + x - v;
            carry += __shfl(x, 63, 64);
        }
        if (tid == 0 && carry > CAP) ovf = 1;
    }
    __syncthreads();
    const bool fits = (ovf == 0);
    if (fits) {   // pass B: scatter src ids into led grouped by local node (binned L2-hot)
        for (int c = tid; c < NC; c += 256) {
            const int gbase = c * CHUNK;
            const int j1 = b1s[c];
            for (int j = b0s[c]; j < j1; ++j) {
                int w = binned[gbase + j];
                int pos = atomicAdd(&cur[w >> 17], 1);
                led[pos] = w & 0x1FFFF;
            }
        }
    }
    __syncthreads();

    for (int local = wv; local < LOCB; local += 4) {
        const int node = b * LOCB + local;
        if (node >= N) break;   // monotone -> uniform break per wave

        const float ivt = invn[node];
        const uint2 ut = *(const uint2*)(xh + (size_t)node * HID + g * 4);
        const float4 xt = h4_to_f4(ut);
        float sd = xt.x*xt.x + xt.y*xt.y + xt.z*xt.z + xt.w*xt.w;
        sd += __shfl_xor(sd, 1, 64); sd += __shfl_xor(sd, 2, 64); sd += __shfl_xor(sd, 4, 64);

        float a0 = 0.f, a1 = 0.f, a2 = 0.f, a3 = 0.f, dsum = 0.f;
        const int deg = cnt[local];

        if (fits) {
            const int st = cur[local] - deg;   // cur ended at start+deg
            for (int e0 = 0; e0 < deg; e0 += 8) {
                const int e = e0 + sub;        // uniform within 8-lane group
                if (e < deg) {
                    const int s_ = led[st + e];
                    const uint2 us = *(const uint2*)(xh + (size_t)s_ * HID + g * 4);
                    const float4 xs = h4_to_f4(us);
                    float p = xt.x*xs.x + xt.y*xs.y + xt.z*xs.z + xt.w*xs.w;
                    p += __shfl_xor(p, 1, 64); p += __shfl_xor(p, 2, 64); p += __shfl_xor(p, 4, 64);
                    const float ivs = invn[s_];
                    const float wgt = __expf(beta * p * ivt * ivs);   // cos in [-1,1]: safe
                    a0 += wgt*xs.x; a1 += wgt*xs.y; a2 += wgt*xs.z; a3 += wgt*xs.w;
                    dsum += wgt;
                }
            }
        } else {
            // fallback (bucket > CAP, practically never): filter all sub-runs from global
            for (int c = 0; c < NC; ++c) {
                const int gbase = c * CHUNK;
                const int j1 = b1s[c];
                for (int j = (int)b0s[c] + sub; j < j1; j += 8) {
                    const int wrd = binned[gbase + j];
                    const bool ok = ((wrd >> 17) == local);
                    const int s_ = ok ? (wrd & 0x1FFFF) : 0;
                    const uint2 us = *(const uint2*)(xh + (size_t)s_ * HID + g * 4);
                    const float4 xs = h4_to_f4(us);
                    float p = xt.x*xs.x + xt.y*xs.y + xt.z*xs.z + xt.w*xs.w;
                    p += __shfl_xor(p, 1, 64); p += __shfl_xor(p, 2, 64); p += __shfl_xor(p, 4, 64);
                    const float ivs = invn[s_];
                    const float wgt = ok ? __expf(beta * p * ivt * ivs) : 0.f;
                    a0 += wgt*xs.x; a1 += wgt*xs.y; a2 += wgt*xs.z; a3 += wgt*xs.w;
                    dsum += wgt;
                }
            }
        }
        #pragma unroll
        for (int m = 8; m <= 32; m <<= 1) {
            a0 += __shfl_xor(a0, m, 64); a1 += __shfl_xor(a1, m, 64);
            a2 += __shfl_xor(a2, m, 64); a3 += __shfl_xor(a3, m, 64);
            dsum += __shfl_xor(dsum, m, 64);
        }
        // self-loop
        const float wself = __expf(beta * sd * ivt * ivt);
        a0 += wself*xt.x; a1 += wself*xt.y; a2 += wself*xt.z; a3 += wself*xt.w;
        dsum += wself;

        const float invd = 1.f / dsum;
        const float o0 = a0*invd, o1 = a1*invd, o2 = a2*invd, o3 = a3*invd;
        float l0 = o0*w0a + o1*w0b + o2*w0c + o3*w0d;
        float l1 = o0*w1a + o1*w1b + o2*w1c + o3*w1d;
        l0 += __shfl_xor(l0, 1, 64); l0 += __shfl_xor(l0, 2, 64); l0 += __shfl_xor(l0, 4, 64);
        l1 += __shfl_xor(l1, 1, 64); l1 += __shfl_xor(l1, 2, 64); l1 += __shfl_xor(l1, 4, 64);
        if (lane == 0) {
            l0 += bb0; l1 += bb1;
            float m = fmaxf(l0, l1);
            float lse = m + __logf(__expf(l0 - m) + __expf(l1 - m));
            out[2 * (size_t)node]     = l0 - lse;
            out[2 * (size_t)node + 1] = l1 - lse;
        }
    }
}

extern "C" void kernel_launch(void* const* d_in, const int* in_sizes, int n_in,
                              void* d_out, int out_size, void* d_ws, size_t ws_size,
                              hipStream_t stream) {
    const float* X    = (const float*)d_in[0];
    const float* w1   = (const float*)d_in[1];
    const float* b1   = (const float*)d_in[2];
    const float* beta = (const float*)d_in[3];
    const float* w2   = (const float*)d_in[4];
    const float* b2   = (const float*)d_in[5];
    const int*   ei   = (const int*)d_in[6];

    const int N = in_sizes[0] / NFEAT;        // 100000
    const int E = in_sizes[6] / 2;            // 1600000
    const int NB = (N + LOCB - 1) / LOCB;     // 782 buckets of 128 nodes
    const int NC = (E + CHUNK - 1) / CHUNK;   // 391 chunks
    const int R  = NB + 1;                    // offset-table row length
    const int nblk1 = (N + 63) / 64;          // 1563 k1 blocks

    char* wsb = (char*)d_ws;
    __half* xhp   = (__half*)wsb;                 wsb += (size_t)N * HID * 2;   // 6.4 MB
    float*  invn  = (float*)wsb;                  wsb += (size_t)N * 4;
    int*    binned = (int*)wsb;                   wsb += (size_t)E * 4;         // 6.4 MB
    unsigned short* offU = (unsigned short*)wsb;  wsb += (size_t)NC * R * 2;    // 0.6 MB
    float* out = (float*)d_out;

    k_phase1<<<nblk1 + NC, 256, 0, stream>>>(X, w1, b1, ei, xhp, invn,
                                             binned, offU, N, E, NB, NC, nblk1);
    k_fused<<<NB, 256, 0, stream>>>(binned, offU, xhp, invn, beta, w2, b2, out, N, NB, NC);
}

// Round 10
// 193.607 us; speedup vs baseline: 2.5946x; 1.1820x over previous
//
#include <hip/hip_runtime.h>
#include <hip/hip_fp16.h>
#include <math.h>

#define HID 32
#define NFEAT 100
#define CHUNK 4096   // edges per sort chunk
#define NCMAX 512    // max chunks (E/CHUNK = 391)
#define NBMAX 1600   // max buckets (N/64 = 1563)
#define LOCB 64      // target nodes per bucket (6-bit local id)
#define CAP 1536     // LDS edge capacity per bucket (mean 1024, sd 32 -> +16 sigma)

typedef _Float16 half2_v __attribute__((ext_vector_type(2)));
__device__ __forceinline__ float2 h2f(unsigned int u) {
    return __half22float2(*(__half2*)&u);
}
__device__ __forceinline__ float4 h4_to_f4(uint2 u) {
    float2 a = h2f(u.x), b = h2f(u.y);
    return make_float4(a.x, a.y, b.x, b.y);
}

// ================= Phase 1: k1 blocks and sort blocks INTERLEAVED (1 of 5) =================
// u%5==4 -> sort chunk u/5; else k1 unit (u/5)*4 + u%5 (64 nodes each).
__global__ __launch_bounds__(256) void k_phase1(
    const float* __restrict__ X, const float* __restrict__ w1,
    const float* __restrict__ b1, const int* __restrict__ ei,
    __half* __restrict__ xh, float* __restrict__ invn,
    int* __restrict__ binned, unsigned short* __restrict__ offU,
    int N, int E, int NB, int NC, int nblk1)
{
    __shared__ __align__(16) char smem[26048];
    const int tid = threadIdx.x;
    const int u = blockIdx.x;
    const int q = u / 5, r = u - q * 5;

    if (r != 4) {
        // ---------------- k1: xh = fp16(relu(X@w1^T+b1)); invn = 1/max(||x||,eps) ----------
        const int blk = q * 4 + r;
        if (blk >= nblk1) return;
        float*   wT  = (float*)smem;                    // [100][33] fp32, 13200 B
        __half2* xsH = (__half2*)(smem + 13216);        // [64][50] half2, 12800 B
        const float4* w14 = (const float4*)w1;          // 800 float4
        for (int i = tid; i < 800; i += 256) {
            float4 v = w14[i];
            int idx = i * 4, h = idx / NFEAT, k = idx % NFEAT;
            wT[k * 33 + h] = v.x; wT[(k + 1) * 33 + h] = v.y;
            wT[(k + 2) * 33 + h] = v.z; wT[(k + 3) * 33 + h] = v.w;
        }
        const int n0 = blk * 64;
        const float4* X4 = (const float4*)X;            // row = 25 float4
        for (int i = tid; i < 1600; i += 256) {
            int rr = i / 25, qq = i % 25;
            int node = n0 + rr;
            float4 v = (node < N) ? X4[(size_t)node * 25 + qq] : make_float4(0.f, 0.f, 0.f, 0.f);
            xsH[rr * 50 + 2 * qq]     = __floats2half2_rn(v.x, v.y);
            xsH[rr * 50 + 2 * qq + 1] = __floats2half2_rn(v.z, v.w);
        }
        __syncthreads();

        const int h  = tid & 31;
        const int ng = tid >> 5;    // node group 0..7 (8 nodes each)
        const float bb = b1[h];
        float d[8] = {0.f, 0.f, 0.f, 0.f, 0.f, 0.f, 0.f, 0.f};

        #pragma unroll 5
        for (int kq = 0; kq < 25; ++kq) {
            const int kb = kq * 4;
            const float wa = wT[kb * 33 + h];
            const float wb = wT[(kb + 1) * 33 + h];
            const float wc = wT[(kb + 2) * 33 + h];
            const float wd = wT[(kb + 3) * 33 + h];
            #pragma unroll
            for (int j = 0; j < 8; ++j) {
                uint2 uu = *(const uint2*)&xsH[(ng * 8 + j) * 50 + 2 * kq];
                float2 fa = h2f(uu.x), fb = h2f(uu.y);
                d[j] = fmaf(fa.x, wa, d[j]);
                d[j] = fmaf(fa.y, wb, d[j]);
                d[j] = fmaf(fb.x, wc, d[j]);
                d[j] = fmaf(fb.y, wd, d[j]);
            }
        }
        #pragma unroll
        for (int j = 0; j < 8; ++j) {
            float v = fmaxf(d[j] + bb, 0.f);
            float s = v * v;
            #pragma unroll
            for (int m = 16; m >= 1; m >>= 1) s += __shfl_xor(s, m, 32);
            float inv = 1.f / fmaxf(sqrtf(s), 1e-12f);
            int node = n0 + ng * 8 + j;
            if (node < N) {
                xh[(size_t)node * HID + h] = __float2half(v);
                if (h == 0) invn[node] = inv;
            }
        }
    } else {
        // ---------------- kc_sort: chunk-local counting sort by bucket = tgt>>6 ------------
        const int c = q;
        if (c >= NC) return;
        int* hist = (int*)smem;          // NBMAX ints
        int* off  = hist + NBMAX;        // NBMAX ints
        const int start = c * CHUNK;
        const int end = min(start + CHUNK, E);
        for (int b = tid; b < NB; b += 256) hist[b] = 0;
        __syncthreads();
        for (int e = start + tid; e < end; e += 256)
            atomicAdd(&hist[ei[E + e] >> 6], 1);
        __syncthreads();
        if (tid < 64) {   // wave 0: exclusive scan, 64 buckets/round with carry
            int carry = 0;
            for (int rr = 0; rr * 64 < NB; ++rr) {
                int b = rr * 64 + tid;
                int v = (b < NB) ? hist[b] : 0;
                int x = v;
                #pragma unroll
                for (int dd = 1; dd < 64; dd <<= 1) {
                    int y = __shfl_up(x, dd, 64);
                    if (tid >= dd) x += y;
                }
                if (b < NB) off[b] = carry + x - v;
                carry += __shfl(x, 63, 64);
            }
        }
        __syncthreads();
        const size_t urow = (size_t)c * (NB + 1);
        for (int b = tid; b < NB; b += 256) {
            offU[urow + b] = (unsigned short)off[b];   // coalesced u16 writes
            hist[b] = off[b];                           // reuse as local cursor
        }
        if (tid == 0) offU[urow + NB] = (unsigned short)(end - start);
        __syncthreads();
        for (int e = start + tid; e < end; e += 256) {
            int t = ei[E + e];
            int b = t >> 6;
            int pos = atomicAdd(&hist[b], 1);
            binned[start + pos] = ei[e] | ((t & 63) << 17);  // src<2^17, local 6 bits
        }
    }
}

// ================= Fused: 1 global pass -> LDS reorder -> pipelined gather =================
__global__ __launch_bounds__(256) void k_fused(
    const int* __restrict__ binned, const unsigned short* __restrict__ offU,
    const __half* __restrict__ xh, const float* __restrict__ invn,
    const float* __restrict__ pbeta,
    const float* __restrict__ w2, const float* __restrict__ b2,
    float* __restrict__ out, int N, int NB, int NC)
{
    __shared__ unsigned short b0s[NCMAX], b1s[NCMAX];
    __shared__ int cnt[LOCB], cur[LOCB];
    __shared__ int led[CAP], led2[CAP];
    __shared__ int bcur_s;
    const int tid  = threadIdx.x;
    const int lane = tid & 63;
    const int wv   = tid >> 6;
    const int g    = lane & 7;   // feature slice: halfs g*4 .. g*4+3
    const int sub  = lane >> 3;  // edge slot 0..7 (slot-uniform across its 8 lanes)
    const int b    = blockIdx.x;
    const int R    = NB + 1;
    const float beta = *pbeta;
    const float w0a = w2[g*4], w0b = w2[g*4+1], w0c = w2[g*4+2], w0d = w2[g*4+3];
    const float w1a = w2[HID+g*4], w1b = w2[HID+g*4+1], w1c = w2[HID+g*4+2], w1d = w2[HID+g*4+3];
    const float bb0 = b2[0], bb1 = b2[1];

    for (int c = tid; c < NC; c += 256) {
        const size_t base = (size_t)c * R + b;
        b0s[c] = offU[base];
        b1s[c] = offU[base + 1];
    }
    if (tid < LOCB) cnt[tid] = 0;
    if (tid == 0) bcur_s = 0;
    __syncthreads();

    // single global pass: append words into led[] unordered + per-node counts
    {
        int total = 0;
        for (int c = tid; c < NC; c += 256) total += (int)b1s[c] - (int)b0s[c];
        int pos = total ? atomicAdd(&bcur_s, total) : 0;
        for (int c = tid; c < NC; c += 256) {
            const int gbase = c * CHUNK;
            const int j1 = b1s[c];
            for (int j = b0s[c]; j < j1; ++j) {
                const int w = binned[gbase + j];
                atomicAdd(&cnt[w >> 17], 1);
                if (pos < CAP) led[pos] = w;
                ++pos;
            }
        }
    }
    __syncthreads();
    const int sz = bcur_s;
    if (tid < 64) {   // exclusive scan of 64 counts
        int v = cnt[tid], x = v;
        #pragma unroll
        for (int dd = 1; dd < 64; dd <<= 1) {
            int y = __shfl_up(x, dd, 64);
            if (tid >= dd) x += y;
        }
        cur[tid] = x - v;
    }
    __syncthreads();
    const bool fits = (sz <= CAP);
    if (fits) {   // LDS->LDS reorder: group src ids by local node
        for (int i = tid; i < sz; i += 256) {
            const int w = led[i];
            const int pos = atomicAdd(&cur[w >> 17], 1);
            led2[pos] = w & 0x1FFFF;
        }
    }
    __syncthreads();

    for (int local = wv; local < LOCB; local += 4) {
        const int node = b * LOCB + local;
        if (node >= N) break;   // monotone -> uniform break per wave

        const float ivt = invn[node];
        const uint2 ut = *(const uint2*)(xh + (size_t)node * HID + g * 4);
        const float4 xt = h4_to_f4(ut);
        float sd = xt.x*xt.x + xt.y*xt.y + xt.z*xt.z + xt.w*xt.w;
        sd += __shfl_xor(sd, 1, 64); sd += __shfl_xor(sd, 2, 64); sd += __shfl_xor(sd, 4, 64);

        float a0 = 0.f, a1 = 0.f, a2 = 0.f, a3 = 0.f, dsum = 0.f;
        const int deg = cnt[local];

        if (fits) {
            const int st = cur[local] - deg;   // cur ended at start+deg
            // software-pipelined: prefetch slot e0+8 while computing slot e0
            bool ok = sub < deg;
            int sc = led2[ok ? st + sub : 0];
            sc = ok ? sc : 0;
            uint2 uc = *(const uint2*)(xh + (size_t)sc * HID + g * 4);
            float ivc = invn[sc];
            for (int e0 = 0; e0 < deg; e0 += 8) {
                const bool okn = (e0 + 8 + sub) < deg;
                int sn = led2[okn ? st + e0 + 8 + sub : 0];
                sn = okn ? sn : 0;
                const uint2 un = *(const uint2*)(xh + (size_t)sn * HID + g * 4);
                const float ivnx = invn[sn];

                const float4 xs = h4_to_f4(uc);
                float p = xt.x*xs.x + xt.y*xs.y + xt.z*xs.z + xt.w*xs.w;
                p += __shfl_xor(p, 1, 64); p += __shfl_xor(p, 2, 64); p += __shfl_xor(p, 4, 64);
                const float wgt = ok ? __expf(beta * p * ivt * ivc) : 0.f;  // cos in [-1,1]
                a0 += wgt*xs.x; a1 += wgt*xs.y; a2 += wgt*xs.z; a3 += wgt*xs.w;
                dsum += wgt;

                uc = un; ivc = ivnx; ok = okn;
            }
        } else {
            // fallback (bucket > CAP, practically never): filter all sub-runs from global
            for (int c = 0; c < NC; ++c) {
                const int gbase = c * CHUNK;
                const int j1 = b1s[c];
                for (int j = (int)b0s[c] + sub; j < j1; j += 8) {
                    const int wrd = binned[gbase + j];
                    const bool ok2 = ((wrd >> 17) == local);
                    const int s_ = ok2 ? (wrd & 0x1FFFF) : 0;
                    const uint2 us = *(const uint2*)(xh + (size_t)s_ * HID + g * 4);
                    const float4 xs = h4_to_f4(us);
                    float p = xt.x*xs.x + xt.y*xs.y + xt.z*xs.z + xt.w*xs.w;
                    p += __shfl_xor(p, 1, 64); p += __shfl_xor(p, 2, 64); p += __shfl_xor(p, 4, 64);
                    const float ivs = invn[s_];
                    const float wgt = ok2 ? __expf(beta * p * ivt * ivs) : 0.f;
                    a0 += wgt*xs.x; a1 += wgt*xs.y; a2 += wgt*xs.z; a3 += wgt*xs.w;
                    dsum += wgt;
                }
            }
        }
        #pragma unroll
        for (int m = 8; m <= 32; m <<= 1) {
            a0 += __shfl_xor(a0, m, 64); a1 += __shfl_xor(a1, m, 64);
            a2 += __shfl_xor(a2, m, 64); a3 += __shfl_xor(a3, m, 64);
            dsum += __shfl_xor(dsum, m, 64);
        }
        // self-loop
        const float wself = __expf(beta * sd * ivt * ivt);
        a0 += wself*xt.x; a1 += wself*xt.y; a2 += wself*xt.z; a3 += wself*xt.w;
        dsum += wself;

        const float invd = 1.f / dsum;
        const float o0 = a0*invd, o1 = a1*invd, o2 = a2*invd, o3 = a3*invd;
        float l0 = o0*w0a + o1*w0b + o2*w0c + o3*w0d;
        float l1 = o0*w1a + o1*w1b + o2*w1c + o3*w1d;
        l0 += __shfl_xor(l0, 1, 64); l0 += __shfl_xor(l0, 2, 64); l0 += __shfl_xor(l0, 4, 64);
        l1 += __shfl_xor(l1, 1, 64); l1 += __shfl_xor(l1, 2, 64); l1 += __shfl_xor(l1, 4, 64);
        if (lane == 0) {
            l0 += bb0; l1 += bb1;
            float m = fmaxf(l0, l1);
            float lse = m + __logf(__expf(l0 - m) + __expf(l1 - m));
            out[2 * (size_t)node]     = l0 - lse;
            out[2 * (size_t)node + 1] = l1 - lse;
        }
    }
}

extern "C" void kernel_launch(void* const* d_in, const int* in_sizes, int n_in,
                              void* d_out, int out_size, void* d_ws, size_t ws_size,
                              hipStream_t stream) {
    const float* X    = (const float*)d_in[0];
    const float* w1   = (const float*)d_in[1];
    const float* b1   = (const float*)d_in[2];
    const float* beta = (const float*)d_in[3];
    const float* w2   = (const float*)d_in[4];
    const float* b2   = (const float*)d_in[5];
    const int*   ei   = (const int*)d_in[6];

    const int N = in_sizes[0] / NFEAT;        // 100000
    const int E = in_sizes[6] / 2;            // 1600000
    const int NB = (N + LOCB - 1) / LOCB;     // 1563 buckets of 64 nodes
    const int NC = (E + CHUNK - 1) / CHUNK;   // 391 chunks
    const int R  = NB + 1;                    // offset-table row length
    const int nblk1 = (N + 63) / 64;          // 1563 k1 units

    char* wsb = (char*)d_ws;
    __half* xhp   = (__half*)wsb;                 wsb += (size_t)N * HID * 2;   // 6.4 MB
    float*  invn  = (float*)wsb;                  wsb += (size_t)N * 4;
    int*    binned = (int*)wsb;                   wsb += (size_t)E * 4;         // 6.4 MB
    unsigned short* offU = (unsigned short*)wsb;  wsb += (size_t)NC * R * 2;    // 1.2 MB
    float* out = (float*)d_out;

    const int k1grp = (nblk1 + 3) / 4;            // 391
    const int gridA = (k1grp > NC ? k1grp : NC) * 5;   // 1955 interleaved blocks

    k_phase1<<<gridA, 256, 0, stream>>>(X, w1, b1, ei, xhp, invn,
                                        binned, offU, N, E, NB, NC, nblk1);
    k_fused<<<NB, 256, 0, stream>>>(binned, offU, xhp, invn, beta, w2, b2, out, N, NB, NC);
}